// Round 11
// baseline (234.559 us; speedup 1.0000x reference)
//
#include <hip/hip_runtime.h>
#include <hip/hip_bf16.h>

typedef __attribute__((ext_vector_type(4))) float f32x4;
typedef __attribute__((ext_vector_type(16))) float f32x16;
typedef __attribute__((ext_vector_type(8))) short bf16x8;

#define GBL_AS(p) (const __attribute__((address_space(1))) void*)(p)
#define LDS_AS(p) (__attribute__((address_space(3))) void*)(p)

__device__ __forceinline__ void gload_lds16(const void* g, void* l) {
  __builtin_amdgcn_global_load_lds(GBL_AS(g), LDS_AS(l), 16, 0, 0);
}

__device__ __forceinline__ ushort f2bf(float f) {
  union { float f; unsigned int u; } v; v.f = f;
  unsigned int r = v.u + 0x7fffu + ((v.u >> 16) & 1u);
  return (ushort)(r >> 16);
}

// ---------------------------------------------------------------- cast f32->bf16
__global__ void cast_f32_bf16_kernel(const float4* __restrict__ in,
                                     ushort4* __restrict__ out, int n4) {
  int i = blockIdx.x * 256 + threadIdx.x;
  if (i < n4) {
    float4 v = in[i];
    ushort4 o;
    o.x = f2bf(v.x); o.y = f2bf(v.y); o.z = f2bf(v.z); o.w = f2bf(v.w);
    out[i] = o;
  }
}

// ------------------------------------------------- transpose + cast: [R][C]f32 -> [C][R]bf16
__global__ void transpose_cast_kernel(const float* __restrict__ in,
                                      ushort* __restrict__ out, int R, int C) {
  __shared__ float tile[64][65];
  int tx = threadIdx.x & 63, ty = threadIdx.x >> 6;
  int r0 = blockIdx.y * 64, c0 = blockIdx.x * 64;
#pragma unroll
  for (int i = 0; i < 64; i += 4)
    tile[ty + i][tx] = in[(size_t)(r0 + ty + i) * C + (c0 + tx)];
  __syncthreads();
#pragma unroll
  for (int i = 0; i < 64; i += 4)
    out[(size_t)(c0 + ty + i) * R + (r0 + tx)] = f2bf(tile[tx][ty + i]);
}

// ---------------------------------------------------------------- 8-phase GEMM (QKV)
// BM=128, BN=256, BK=64. 8 waves (2M x 4N), wave tile 64x64 = acc[4][4].
// LDS 96KB: per buf {A:16KB, B:32KB}; grid 768 = exactly 3 block-waves.
// Per K-tile: 4 phases x 8 MFMA; counted vmcnt(4)@ph3 / vmcnt(6)@ph7
// (per-thread ledger verified); staging slots placed by liveness analysis.
// QKV scatter epilogue: Q scaled by log2(e)/sqrt(128) -> [B*H][S][D];
// K -> [B*H][S][D]; V -> transposed [B*H][D][S].
__global__ __launch_bounds__(512, 2) void gemm8p_kernel(
    const ushort* __restrict__ A, const ushort* __restrict__ Bt,
    const float* __restrict__ bias, ushort* __restrict__ Qo,
    ushort* __restrict__ Ko, ushort* __restrict__ Vo, int M, int N, int K) {
  __shared__ char lds[2][49152];  // per buf: A0@0, A1@8K, B0@16K, B1@32K

  const int tid = threadIdx.x;
  const int w = tid >> 6, l = tid & 63;
  const int wm = w >> 2, wn = w & 3;
  const int l15 = l & 15, l4 = l >> 4;
  const int lr = l >> 3, lc = (l & 7) ^ lr;

  // XCD swizzle: 768 = 8*96; per-XCD gets 3 N-columns (B-panels 3MB, L2-fit)
  const int bid = blockIdx.x;
  const int swz = (bid & 7) * 96 + (bid >> 3);
  const int by = swz & 31, bx = swz >> 5;
  const int m0 = by * 128, n0 = bx * 256;

  f32x4 acc[4][4] = {};
  const int NT = K >> 6;

  // stage A half h (64 rows x 64 cols, 8KB): 1 load/thread
  auto stageA = [&](int t, int h) {
    int row = h * 64 + w * 8 + lr;
    gload_lds16(A + (size_t)(m0 + row) * K + t * 64 + lc * 8,
                lds[t & 1] + h * 8192 + w * 1024);
  };
  // stage B half h (128 rows, 16KB): 2 loads/thread
  auto stageB = [&](int t, int h) {
#pragma unroll
    for (int s = 0; s < 2; ++s) {
      int i = w * 2 + s;
      int row = h * 128 + i * 8 + lr;
      gload_lds16(Bt + (size_t)(n0 + row) * K + t * 64 + lc * 8,
                  lds[t & 1] + 16384 + h * 16384 + i * 1024);
    }
  };

  auto rdA2 = [&](bf16x8* a, int buf, int mi0) {
    const char* Ab = lds[buf] + wm * 8192;
#pragma unroll
    for (int mi = 0; mi < 2; ++mi) {
      int row = (mi0 + mi) * 16 + l15;
      int sw = row & 7;
#pragma unroll
      for (int ks = 0; ks < 2; ++ks) {
        int c = ks * 4 + l4;
        a[mi * 2 + ks] = *(const bf16x8*)(Ab + row * 128 + ((c ^ sw) << 4));
      }
    }
  };
  auto rdB2 = [&](bf16x8* b, int buf, int ni0) {
    const char* Bb = lds[buf] + 16384 + (wn >> 1) * 16384;
#pragma unroll
    for (int ni = 0; ni < 2; ++ni) {
      int row = (wn & 1) * 64 + (ni0 + ni) * 16 + l15;
      int sw = row & 7;
#pragma unroll
      for (int ks = 0; ks < 2; ++ks) {
        int c = ks * 4 + l4;
        b[ni * 2 + ks] = *(const bf16x8*)(Bb + row * 128 + ((c ^ sw) << 4));
      }
    }
  };
  auto quad8 = [&](const bf16x8* a, const bf16x8* b, int mi0, int ni0) {
    __builtin_amdgcn_s_setprio(1);
#pragma unroll
    for (int mi = 0; mi < 2; ++mi)
#pragma unroll
      for (int ni = 0; ni < 2; ++ni)
#pragma unroll
        for (int ks = 0; ks < 2; ++ks)
          acc[mi0 + mi][ni0 + ni] = __builtin_amdgcn_mfma_f32_16x16x32_bf16(
              a[mi * 2 + ks], b[ni * 2 + ks], acc[mi0 + mi][ni0 + ni], 0, 0, 0);
    __builtin_amdgcn_s_setprio(0);
  };

#define BAR __builtin_amdgcn_s_barrier()
#define LGKM0 asm volatile("s_waitcnt lgkmcnt(0)" ::: "memory")

  // prologue: tiles 0,1 (6 loads each); drain tile 0
  stageB(0, 0); stageA(0, 0); stageA(0, 1); stageB(0, 1);
  stageB(1, 0); stageA(1, 0); stageA(1, 1); stageB(1, 1);
  asm volatile("s_waitcnt vmcnt(6)" ::: "memory");
  BAR;

  for (int i2 = 0; i2 < (NT >> 1); ++i2) {
    const int ta = 2 * i2, tb = ta + 1;
    const bool sA = ta + 2 < NT, sB = tb + 2 < NT;
    bf16x8 aa[4], b01[4], b23[4];

    // ph0 (buf0): a[0:2], b01
    rdA2(aa, 0, 0); rdB2(b01, 0, 0);
    BAR; LGKM0; quad8(aa, b01, 0, 0); BAR;
    // ph1: b23
    rdB2(b23, 0, 2);
    BAR; LGKM0; quad8(aa, b23, 0, 2); BAR;
    // ph2: a[2:4]; stage B0(ta+2)
    rdA2(aa, 0, 2);
    if (sA) stageB(ta + 2, 0);
    BAR; LGKM0; quad8(aa, b01, 2, 0); BAR;
    // ph3: stage A0,A1(ta+2); vmcnt -> tile tb landed
    if (sA) { stageA(ta + 2, 0); stageA(ta + 2, 1); }
    if (sA) asm volatile("s_waitcnt vmcnt(4)" ::: "memory");
    else    asm volatile("s_waitcnt vmcnt(0)" ::: "memory");
    BAR; LGKM0; quad8(aa, b23, 2, 2); BAR;
    // ph4 (buf1): a[0:2], b01; stage B1(ta+2)
    rdA2(aa, 1, 0); rdB2(b01, 1, 0);
    if (sA) stageB(ta + 2, 1);
    BAR; LGKM0; quad8(aa, b01, 0, 0); BAR;
    // ph5: b23
    rdB2(b23, 1, 2);
    BAR; LGKM0; quad8(aa, b23, 0, 2); BAR;
    // ph6: a[2:4]; stage B0(tb+2)
    rdA2(aa, 1, 2);
    if (sB) stageB(tb + 2, 0);
    BAR; LGKM0; quad8(aa, b01, 2, 0); BAR;
    // ph7: stage B1,A0,A1(tb+2); vmcnt -> tile ta+2 landed
    if (sB) { stageB(tb + 2, 1); stageA(tb + 2, 0); stageA(tb + 2, 1); }
    if (sB) asm volatile("s_waitcnt vmcnt(6)" ::: "memory");
    else    asm volatile("s_waitcnt vmcnt(0)" ::: "memory");
    BAR; LGKM0; quad8(aa, b23, 2, 2); BAR;
  }
#undef BAR
#undef LGKM0

  // QKV scatter epilogue (same mapping as verified 128^2 kernel)
  const float qscale = 0.08838834764831845f * 1.4426950408889634f;
#pragma unroll
  for (int ni = 0; ni < 4; ++ni) {
    int n = n0 + wn * 64 + ni * 16 + l15;
    int which = n >> 11;
    int cc2 = n & 2047;
    int h = cc2 >> 7, d = cc2 & 127;
    float b = bias[n];
#pragma unroll
    for (int mi = 0; mi < 4; ++mi) {
      int m = m0 + wm * 64 + mi * 16 + (l4 << 2);
      int bb = m >> 11, s = m & 2047;
      int bh = bb * 16 + h;
      if (which == 0) {
#pragma unroll
        for (int r = 0; r < 4; ++r)
          Qo[((size_t)bh * 2048 + s + r) * 128 + d] =
              f2bf((acc[mi][ni][r] + b) * qscale);
      } else if (which == 1) {
#pragma unroll
        for (int r = 0; r < 4; ++r)
          Ko[((size_t)bh * 2048 + s + r) * 128 + d] = f2bf(acc[mi][ni][r] + b);
      } else {
        ushort4 pk;
        pk.x = f2bf(acc[mi][ni][0] + b);
        pk.y = f2bf(acc[mi][ni][1] + b);
        pk.z = f2bf(acc[mi][ni][2] + b);
        pk.w = f2bf(acc[mi][ni][3] + b);
        *(ushort4*)(Vo + ((size_t)bh * 128 + d) * 2048 + s) = pk;
      }
    }
  }
}

// ---------------------------------------------------------------- 128x128 GEMM (GEMM2)
__global__ __launch_bounds__(256, 2) void gemm_bt_kernel(
    const ushort* __restrict__ A, const ushort* __restrict__ Bt,
    const float* __restrict__ bias, float* __restrict__ C, int M, int N,
    int K) {
  __shared__ ushort As[128 * 64];
  __shared__ ushort Bs[128 * 64];
  const int tid = threadIdx.x;
  const int w = tid >> 6, l = tid & 63;
  const int wr = w >> 1, wc = w & 1;
  const int m0 = blockIdx.y * 128, n0 = blockIdx.x * 128;

  f32x4 acc[4][4] = {};

  const int lr = l >> 3;
  const int lc = (l & 7) ^ lr;

  for (int k0 = 0; k0 < K; k0 += 64) {
#pragma unroll
    for (int i = 0; i < 4; ++i) {
      int row = i * 32 + w * 8 + lr;
      gload_lds16(A + (size_t)(m0 + row) * K + k0 + lc * 8,
                  (char*)As + (i * 32 + w * 8) * 128);
      gload_lds16(Bt + (size_t)(n0 + row) * K + k0 + lc * 8,
                  (char*)Bs + (i * 32 + w * 8) * 128);
    }
    __syncthreads();
    const char* Ab = (const char*)As;
    const char* Bb = (const char*)Bs;
#pragma unroll
    for (int ks = 0; ks < 2; ++ks) {
      bf16x8 af[4], bfr[4];
      int cc = ks * 4 + (l >> 4);
#pragma unroll
      for (int mi = 0; mi < 4; ++mi) {
        int row = wr * 64 + mi * 16 + (l & 15);
        af[mi] = *(const bf16x8*)(Ab + row * 128 + ((cc ^ (row & 7)) << 4));
      }
#pragma unroll
      for (int ni = 0; ni < 4; ++ni) {
        int row = wc * 64 + ni * 16 + (l & 15);
        bfr[ni] = *(const bf16x8*)(Bb + row * 128 + ((cc ^ (row & 7)) << 4));
      }
#pragma unroll
      for (int mi = 0; mi < 4; ++mi)
#pragma unroll
        for (int ni = 0; ni < 4; ++ni)
          acc[mi][ni] = __builtin_amdgcn_mfma_f32_16x16x32_bf16(
              af[mi], bfr[ni], acc[mi][ni], 0, 0, 0);
    }
    __syncthreads();
  }

#pragma unroll
  for (int mi = 0; mi < 4; ++mi) {
    int row = m0 + wr * 64 + mi * 16 + ((l >> 4) << 2);
#pragma unroll
    for (int ni = 0; ni < 4; ++ni) {
      int col = n0 + wc * 64 + ni * 16 + (l & 15);
      float b = bias[col];
#pragma unroll
      for (int rr = 0; rr < 4; ++rr)
        C[(size_t)(row + rr) * N + col] = acc[mi][ni][rr] + b;
    }
  }
}

// ---------------------------------------------------------------- flash attention
// Swapped-QK^T, KVBLK=128 (round-10 best): S^T = mfma_32x32x16(A=K, B=Q);
// in-register softmax (exp2, defer-max); cvt_pk+permlane P->bf16; K,V dbuf
// 32KB tiles (128KB LDS). 8-wave paired blocks (heavy qb=8+j, light 7-j).
__global__ __launch_bounds__(512, 2) void attn_kernel(
    const ushort* __restrict__ Qg, const ushort* __restrict__ Kg,
    const ushort* __restrict__ Vtg, ushort* __restrict__ Og) {
  constexpr int S = 2048, D = 128;
  __shared__ ushort Kl[2][128 * 128];
  __shared__ ushort Vl[2][128 * 128];

  const int tid = threadIdx.x, w = tid >> 6, l = tid & 63;
  const int lid = blockIdx.x;
  const int bh = lid & 31;
  const int j = lid >> 5;
  const int g = w >> 2, wv = w & 3;
  const int qb = (g == 0) ? (8 + j) : (7 - j);
  const int wq0 = qb * 128 + wv * 32;
  const int nt_blk = 9 + j;
  const int ql = l & 31, h32 = l >> 5;

  const ushort* Qb = Qg + (size_t)bh * S * D;
  const ushort* Kb = Kg + (size_t)bh * S * D;
  const ushort* Vb = Vtg + (size_t)bh * D * S;

  bf16x8 qf[8];
#pragma unroll
  for (int ks = 0; ks < 8; ++ks)
    qf[ks] = *(const bf16x8*)(Qb + (size_t)(wq0 + ql) * D + ks * 16 + h32 * 8);

  f32x16 o[4];
#pragma unroll
  for (int dt = 0; dt < 4; ++dt) o[dt] = 0.f;
  float mrun = -1e30f, lrun = 0.f;

  auto stage = [&](int t, int buf) {
    const int k0 = t * 128;
#pragma unroll
    for (int s2 = 0; s2 < 4; ++s2) {
      int i = w * 4 + s2;
      int row = i * 4 + (l >> 4);
      int ck = (l & 15) ^ (row & 7);
      gload_lds16(Kb + (size_t)(k0 + row) * D + ck * 8,
                  (char*)Kl[buf] + i * 1024);
    }
#pragma unroll
    for (int s2 = 0; s2 < 4; ++s2) {
      int i = w * 4 + s2;
      int row = i * 4 + (l >> 4);
      int ck = (l & 15) ^ (row & 7);
      gload_lds16(Vb + (size_t)row * S + k0 + ck * 8,
                  (char*)Vl[buf] + i * 1024);
    }
  };

  stage(0, 0);

  for (int t = 0; t < nt_blk; ++t) {
    const int cur = t & 1;
    const int k0 = t * 128;
    if (t + 1 < nt_blk) {
      stage(t + 1, cur ^ 1);
      asm volatile("s_waitcnt vmcnt(8)" ::: "memory");
    } else {
      asm volatile("s_waitcnt vmcnt(0)" ::: "memory");
    }
    __builtin_amdgcn_s_barrier();

    if (k0 < wq0 + 32) {
      const char* Kc = (const char*)Kl[cur];
      const char* Vc = (const char*)Vl[cur];
      const int swz0 = ql & 7;

      f32x16 sa[4];
#pragma unroll
      for (int kt = 0; kt < 4; ++kt) sa[kt] = 0.f;
#pragma unroll
      for (int p = 0; p < 2; ++p) {
        bf16x8 kf0[8], kf1[8];
        const char* base0 = Kc + (p * 64 + ql) * 256;
        const char* base1 = Kc + (p * 64 + 32 + ql) * 256;
#pragma unroll
        for (int ks = 0; ks < 8; ++ks) {
          int c = 2 * ks + h32;
          kf0[ks] = *(const bf16x8*)(base0 + ((c ^ swz0) << 4));
          kf1[ks] = *(const bf16x8*)(base1 + ((c ^ swz0) << 4));
        }
        __builtin_amdgcn_s_setprio(1);
#pragma unroll
        for (int ks = 0; ks < 8; ++ks) {
          sa[p * 2] = __builtin_amdgcn_mfma_f32_32x32x16_bf16(
              kf0[ks], qf[ks], sa[p * 2], 0, 0, 0);
          sa[p * 2 + 1] = __builtin_amdgcn_mfma_f32_32x32x16_bf16(
              kf1[ks], qf[ks], sa[p * 2 + 1], 0, 0, 0);
        }
        __builtin_amdgcn_s_setprio(0);
      }

      if (k0 + 127 > wq0) {
        int qq = wq0 + ql;
#pragma unroll
        for (int kt = 0; kt < 4; ++kt) {
          int kb = k0 + kt * 32 + 4 * h32;
#pragma unroll
          for (int rr = 0; rr < 16; ++rr) {
            int kk = kb + (rr & 3) + 8 * (rr >> 2);
            if (qq < kk) sa[kt][rr] = -1e9f;
          }
        }
      }

      float tmax = -1e30f;
#pragma unroll
      for (int kt = 0; kt < 4; ++kt)
#pragma unroll
        for (int rr = 0; rr < 16; ++rr) tmax = fmaxf(tmax, sa[kt][rr]);
      tmax = fmaxf(tmax, __shfl_xor(tmax, 32));

      if (!__all(tmax <= mrun + 11.5f)) {
        float mnew = fmaxf(mrun, tmax);
        float e = __builtin_amdgcn_exp2f(mrun - mnew);
        lrun *= e;
        mrun = mnew;
#pragma unroll
        for (int dt = 0; dt < 4; ++dt) o[dt] *= e;
      }

      float rsum = 0.f;
#pragma unroll
      for (int kt = 0; kt < 4; ++kt)
#pragma unroll
        for (int rr = 0; rr < 16; ++rr) {
          float p = __builtin_amdgcn_exp2f(sa[kt][rr] - mrun);
          sa[kt][rr] = p;
          rsum += p;
        }
      rsum += __shfl_xor(rsum, 32);
      lrun += rsum;

#pragma unroll
      for (int kt = 0; kt < 4; ++kt) {
#pragma unroll
        for (int u2 = 0; u2 < 2; ++u2) {
          int c = 4 * kt + 2 * u2 + h32;
          bf16x8 vf[4];
#pragma unroll
          for (int dt = 0; dt < 4; ++dt) {
            int row = dt * 32 + ql;
            vf[dt] = *(const bf16x8*)(Vc + row * 256 + ((c ^ swz0) << 4));
          }
          int A0, B0, A1, B1;
          asm("v_cvt_pk_bf16_f32 %0, %1, %2"
              : "=v"(A0) : "v"(sa[kt][u2 * 8 + 0]), "v"(sa[kt][u2 * 8 + 1]));
          asm("v_cvt_pk_bf16_f32 %0, %1, %2"
              : "=v"(B0) : "v"(sa[kt][u2 * 8 + 2]), "v"(sa[kt][u2 * 8 + 3]));
          asm("v_cvt_pk_bf16_f32 %0, %1, %2"
              : "=v"(A1) : "v"(sa[kt][u2 * 8 + 4]), "v"(sa[kt][u2 * 8 + 5]));
          asm("v_cvt_pk_bf16_f32 %0, %1, %2"
              : "=v"(B1) : "v"(sa[kt][u2 * 8 + 6]), "v"(sa[kt][u2 * 8 + 7]));
          auto r02 = __builtin_amdgcn_permlane32_swap(A0, A1, false, false);
          auto r13 = __builtin_amdgcn_permlane32_swap(B0, B1, false, false);
          union { int i[4]; bf16x8 v; } pu;
          pu.i[0] = r02[0];
          pu.i[1] = r13[0];
          pu.i[2] = r02[1];
          pu.i[3] = r13[1];
          __builtin_amdgcn_s_setprio(1);
#pragma unroll
          for (int dt = 0; dt < 4; ++dt)
            o[dt] = __builtin_amdgcn_mfma_f32_32x32x16_bf16(vf[dt], pu.v, o[dt],
                                                            0, 0, 0);
          __builtin_amdgcn_s_setprio(0);
        }
      }
    }
    asm volatile("s_waitcnt lgkmcnt(0)" ::: "memory");
    __builtin_amdgcn_s_barrier();
  }

  const int b = bh >> 4, h = bh & 15;
  float inv = 1.0f / lrun;
  size_t rowbase = ((size_t)b * 2048 + (wq0 + ql)) * 2048 + h * 128;
#pragma unroll
  for (int dt = 0; dt < 4; ++dt)
#pragma unroll
    for (int r4 = 0; r4 < 4; ++r4) {
      int col = dt * 32 + r4 * 8 + h32 * 4;
      ushort4 pk;
      pk.x = f2bf(o[dt][r4 * 4 + 0] * inv);
      pk.y = f2bf(o[dt][r4 * 4 + 1] * inv);
      pk.z = f2bf(o[dt][r4 * 4 + 2] * inv);
      pk.w = f2bf(o[dt][r4 * 4 + 3] * inv);
      *(ushort4*)(Og + rowbase + col) = pk;
    }
}

// ---------------------------------------------------------------- launch
extern "C" void kernel_launch(void* const* d_in, const int* in_sizes, int n_in,
                              void* d_out, int out_size, void* d_ws,
                              size_t ws_size, hipStream_t stream) {
  const float* x = (const float*)d_in[0];
  const float* w_qkv = (const float*)d_in[1];
  const float* b_qkv = (const float*)d_in[2];
  const float* w_out = (const float*)d_in[3];
  const float* b_out = (const float*)d_in[4];
  float* out = (float*)d_out;
  char* ws = (char*)d_ws;

  if (ws_size < 92274688u) return;
  ushort* xb = (ushort*)(ws);
  ushort* wqkvt = (ushort*)(ws + 16777216);
  ushort* Q = (ushort*)(ws + 41943040);
  ushort* Kb = (ushort*)(ws + 58720256);
  ushort* Vt = (ushort*)(ws + 75497472);
  ushort* comb = xb;
  ushort* woutt = wqkvt;

  cast_f32_bf16_kernel<<<8192, 256, 0, stream>>>((const float4*)x, (ushort4*)xb,
                                                 2097152);
  transpose_cast_kernel<<<dim3(96, 32), 256, 0, stream>>>(w_qkv, wqkvt, 2048,
                                                          6144);
  gemm8p_kernel<<<dim3(768), 512, 0, stream>>>(xb, wqkvt, b_qkv, Q, Kb, Vt,
                                               4096, 6144, 2048);
  transpose_cast_kernel<<<dim3(32, 32), 256, 0, stream>>>(w_out, woutt, 2048,
                                                          2048);
  attn_kernel<<<dim3(256), 512, 0, stream>>>(Q, Kb, Vt, comb);
  gemm_bt_kernel<<<dim3(16, 32), 256, 0, stream>>>(comb, woutt, b_out, out,
                                                   4096, 2048, 2048);
}

// Round 12
// 220.952 us; speedup vs baseline: 1.0616x; 1.0616x over previous
//
#include <hip/hip_runtime.h>
#include <hip/hip_bf16.h>

typedef __attribute__((ext_vector_type(4))) float f32x4;
typedef __attribute__((ext_vector_type(16))) float f32x16;
typedef __attribute__((ext_vector_type(8))) short bf16x8;

#define GBL_AS(p) (const __attribute__((address_space(1))) void*)(p)
#define LDS_AS(p) (__attribute__((address_space(3))) void*)(p)

__device__ __forceinline__ void gload_lds16(const void* g, void* l) {
  __builtin_amdgcn_global_load_lds(GBL_AS(g), LDS_AS(l), 16, 0, 0);
}

__device__ __forceinline__ ushort f2bf(float f) {
  union { float f; unsigned int u; } v; v.f = f;
  unsigned int r = v.u + 0x7fffu + ((v.u >> 16) & 1u);
  return (ushort)(r >> 16);
}

// ---------------------------------------------------------------- fused prep:
// blocks [0,8192): cast x f32->bf16 (float4/ushort4 chunks)
// blocks [8192,11264): transpose+cast w_qkv [2048][6144] -> [6144][2048] bf16
__global__ void prep_kernel(const float4* __restrict__ x4,
                            ushort4* __restrict__ xb4,
                            const float* __restrict__ wqkv,
                            ushort* __restrict__ wqkvt) {
  __shared__ float tile[64][65];
  const int blk = blockIdx.x;
  if (blk < 8192) {
    int i = blk * 256 + threadIdx.x;
    float4 v = x4[i];
    ushort4 o;
    o.x = f2bf(v.x); o.y = f2bf(v.y); o.z = f2bf(v.z); o.w = f2bf(v.w);
    xb4[i] = o;
  } else {
    const int idx = blk - 8192;
    const int bx = idx % 96, by = idx / 96;   // 96 x 32 tiles
    const int C = 6144, R = 2048;
    int tx = threadIdx.x & 63, ty = threadIdx.x >> 6;
    int r0 = by * 64, c0 = bx * 64;
#pragma unroll
    for (int i = 0; i < 64; i += 4)
      tile[ty + i][tx] = wqkv[(size_t)(r0 + ty + i) * C + (c0 + tx)];
    __syncthreads();
#pragma unroll
    for (int i = 0; i < 64; i += 4)
      wqkvt[(size_t)(c0 + ty + i) * R + (r0 + tx)] = f2bf(tile[tx][ty + i]);
  }
}

// ------------------------------------------------- transpose + cast: [R][C]f32 -> [C][R]bf16
__global__ void transpose_cast_kernel(const float* __restrict__ in,
                                      ushort* __restrict__ out, int R, int C) {
  __shared__ float tile[64][65];
  int tx = threadIdx.x & 63, ty = threadIdx.x >> 6;
  int r0 = blockIdx.y * 64, c0 = blockIdx.x * 64;
#pragma unroll
  for (int i = 0; i < 64; i += 4)
    tile[ty + i][tx] = in[(size_t)(r0 + ty + i) * C + (c0 + tx)];
  __syncthreads();
#pragma unroll
  for (int i = 0; i < 64; i += 4)
    out[(size_t)(c0 + ty + i) * R + (r0 + tx)] = f2bf(tile[tx][ty + i]);
}

// ---------------------------------------------------------------- bf16 GEMM, Bt layout
// A: [M][K] bf16, Bt: [N][K] bf16.  MODE 0: C=f32 [M][N] + bias.
// MODE 1: QKV scatter: Q scaled by log2(e)/sqrt(128) -> [B*H][S][D];
//         K -> [B*H][S][D]; V -> transposed [B*H][D][S].
template <int MODE>
__global__ __launch_bounds__(256, 2) void gemm_bt_kernel(
    const ushort* __restrict__ A, const ushort* __restrict__ Bt,
    const float* __restrict__ bias, float* __restrict__ C,
    ushort* __restrict__ Qo, ushort* __restrict__ Ko, ushort* __restrict__ Vo,
    int M, int N, int K) {
  __shared__ ushort As[128 * 64];
  __shared__ ushort Bs[128 * 64];
  const int tid = threadIdx.x;
  const int w = tid >> 6, l = tid & 63;
  const int wr = w >> 1, wc = w & 1;
  const int m0 = blockIdx.y * 128, n0 = blockIdx.x * 128;

  f32x4 acc[4][4] = {};

  const int lr = l >> 3;             // row-in-1KB-group (0..7)
  const int lc = (l & 7) ^ lr;       // pre-swizzled source chunk

  for (int k0 = 0; k0 < K; k0 += 64) {
#pragma unroll
    for (int i = 0; i < 4; ++i) {
      int row = i * 32 + w * 8 + lr;
      gload_lds16(A + (size_t)(m0 + row) * K + k0 + lc * 8,
                  (char*)As + (i * 32 + w * 8) * 128);
      gload_lds16(Bt + (size_t)(n0 + row) * K + k0 + lc * 8,
                  (char*)Bs + (i * 32 + w * 8) * 128);
    }
    __syncthreads();
    const char* Ab = (const char*)As;
    const char* Bb = (const char*)Bs;
#pragma unroll
    for (int ks = 0; ks < 2; ++ks) {
      bf16x8 af[4], bfr[4];
      int cc = ks * 4 + (l >> 4);
#pragma unroll
      for (int mi = 0; mi < 4; ++mi) {
        int row = wr * 64 + mi * 16 + (l & 15);
        af[mi] = *(const bf16x8*)(Ab + row * 128 + ((cc ^ (row & 7)) << 4));
      }
#pragma unroll
      for (int ni = 0; ni < 4; ++ni) {
        int row = wc * 64 + ni * 16 + (l & 15);
        bfr[ni] = *(const bf16x8*)(Bb + row * 128 + ((cc ^ (row & 7)) << 4));
      }
#pragma unroll
      for (int mi = 0; mi < 4; ++mi)
#pragma unroll
        for (int ni = 0; ni < 4; ++ni)
          acc[mi][ni] = __builtin_amdgcn_mfma_f32_16x16x32_bf16(
              af[mi], bfr[ni], acc[mi][ni], 0, 0, 0);
    }
    __syncthreads();
  }

  if (MODE == 0) {
#pragma unroll
    for (int mi = 0; mi < 4; ++mi) {
      int row = m0 + wr * 64 + mi * 16 + ((l >> 4) << 2);
#pragma unroll
      for (int ni = 0; ni < 4; ++ni) {
        int col = n0 + wc * 64 + ni * 16 + (l & 15);
        float b = bias[col];
#pragma unroll
        for (int r = 0; r < 4; ++r)
          C[(size_t)(row + r) * N + col] = acc[mi][ni][r] + b;
      }
    }
  } else {
    // log2(e)/sqrt(128): softmax runs in exp2 domain
    const float qscale = 0.08838834764831845f * 1.4426950408889634f;
#pragma unroll
    for (int ni = 0; ni < 4; ++ni) {
      int n = n0 + wc * 64 + ni * 16 + (l & 15);
      int which = n >> 11;
      int cc2 = n & 2047;
      int h = cc2 >> 7, d = cc2 & 127;
      float b = bias[n];
#pragma unroll
      for (int mi = 0; mi < 4; ++mi) {
        int m = m0 + wr * 64 + mi * 16 + ((l >> 4) << 2);
        int bb = m >> 11, s = m & 2047;
        int bh = bb * 16 + h;
        if (which == 0) {
#pragma unroll
          for (int r = 0; r < 4; ++r)
            Qo[((size_t)bh * 2048 + s + r) * 128 + d] =
                f2bf((acc[mi][ni][r] + b) * qscale);
        } else if (which == 1) {
#pragma unroll
          for (int r = 0; r < 4; ++r)
            Ko[((size_t)bh * 2048 + s + r) * 128 + d] = f2bf(acc[mi][ni][r] + b);
        } else {
          ushort4 pk;
          pk.x = f2bf(acc[mi][ni][0] + b);
          pk.y = f2bf(acc[mi][ni][1] + b);
          pk.z = f2bf(acc[mi][ni][2] + b);
          pk.w = f2bf(acc[mi][ni][3] + b);
          *(ushort4*)(Vo + ((size_t)bh * 128 + d) * 2048 + s) = pk;
        }
      }
    }
  }
}

// ---------------------------------------------------------------- flash attention
// Swapped-QK^T, KVBLK=128 (round-10 best): S^T = mfma_32x32x16(A=K, B=Q);
// in-register softmax (exp2, defer-max); cvt_pk+permlane P->bf16; K,V dbuf
// 32KB tiles (128KB LDS). 8-wave paired blocks (heavy qb=8+j, light 7-j).
__global__ __launch_bounds__(512, 2) void attn_kernel(
    const ushort* __restrict__ Qg, const ushort* __restrict__ Kg,
    const ushort* __restrict__ Vtg, ushort* __restrict__ Og) {
  constexpr int S = 2048, D = 128;
  __shared__ ushort Kl[2][128 * 128];
  __shared__ ushort Vl[2][128 * 128];

  const int tid = threadIdx.x, w = tid >> 6, l = tid & 63;
  const int lid = blockIdx.x;
  const int bh = lid & 31;
  const int j = lid >> 5;
  const int g = w >> 2, wv = w & 3;
  const int qb = (g == 0) ? (8 + j) : (7 - j);
  const int wq0 = qb * 128 + wv * 32;
  const int nt_blk = 9 + j;
  const int ql = l & 31, h32 = l >> 5;

  const ushort* Qb = Qg + (size_t)bh * S * D;
  const ushort* Kb = Kg + (size_t)bh * S * D;
  const ushort* Vb = Vtg + (size_t)bh * D * S;

  bf16x8 qf[8];
#pragma unroll
  for (int ks = 0; ks < 8; ++ks)
    qf[ks] = *(const bf16x8*)(Qb + (size_t)(wq0 + ql) * D + ks * 16 + h32 * 8);

  f32x16 o[4];
#pragma unroll
  for (int dt = 0; dt < 4; ++dt) o[dt] = 0.f;
  float mrun = -1e30f, lrun = 0.f;

  auto stage = [&](int t, int buf) {
    const int k0 = t * 128;
#pragma unroll
    for (int s2 = 0; s2 < 4; ++s2) {
      int i = w * 4 + s2;
      int row = i * 4 + (l >> 4);
      int ck = (l & 15) ^ (row & 7);
      gload_lds16(Kb + (size_t)(k0 + row) * D + ck * 8,
                  (char*)Kl[buf] + i * 1024);
    }
#pragma unroll
    for (int s2 = 0; s2 < 4; ++s2) {
      int i = w * 4 + s2;
      int row = i * 4 + (l >> 4);
      int ck = (l & 15) ^ (row & 7);
      gload_lds16(Vb + (size_t)row * S + k0 + ck * 8,
                  (char*)Vl[buf] + i * 1024);
    }
  };

  stage(0, 0);

  for (int t = 0; t < nt_blk; ++t) {
    const int cur = t & 1;
    const int k0 = t * 128;
    if (t + 1 < nt_blk) {
      stage(t + 1, cur ^ 1);
      asm volatile("s_waitcnt vmcnt(8)" ::: "memory");
    } else {
      asm volatile("s_waitcnt vmcnt(0)" ::: "memory");
    }
    __builtin_amdgcn_s_barrier();

    if (k0 < wq0 + 32) {
      const char* Kc = (const char*)Kl[cur];
      const char* Vc = (const char*)Vl[cur];
      const int swz0 = ql & 7;

      f32x16 sa[4];
#pragma unroll
      for (int kt = 0; kt < 4; ++kt) sa[kt] = 0.f;
#pragma unroll
      for (int p = 0; p < 2; ++p) {
        bf16x8 kf0[8], kf1[8];
        const char* base0 = Kc + (p * 64 + ql) * 256;
        const char* base1 = Kc + (p * 64 + 32 + ql) * 256;
#pragma unroll
        for (int ks = 0; ks < 8; ++ks) {
          int c = 2 * ks + h32;
          kf0[ks] = *(const bf16x8*)(base0 + ((c ^ swz0) << 4));
          kf1[ks] = *(const bf16x8*)(base1 + ((c ^ swz0) << 4));
        }
        __builtin_amdgcn_s_setprio(1);
#pragma unroll
        for (int ks = 0; ks < 8; ++ks) {
          sa[p * 2] = __builtin_amdgcn_mfma_f32_32x32x16_bf16(
              kf0[ks], qf[ks], sa[p * 2], 0, 0, 0);
          sa[p * 2 + 1] = __builtin_amdgcn_mfma_f32_32x32x16_bf16(
              kf1[ks], qf[ks], sa[p * 2 + 1], 0, 0, 0);
        }
        __builtin_amdgcn_s_setprio(0);
      }

      if (k0 + 127 > wq0) {
        int qq = wq0 + ql;
#pragma unroll
        for (int kt = 0; kt < 4; ++kt) {
          int kb = k0 + kt * 32 + 4 * h32;
#pragma unroll
          for (int rr = 0; rr < 16; ++rr) {
            int kk = kb + (rr & 3) + 8 * (rr >> 2);
            if (qq < kk) sa[kt][rr] = -1e9f;
          }
        }
      }

      float tmax = -1e30f;
#pragma unroll
      for (int kt = 0; kt < 4; ++kt)
#pragma unroll
        for (int rr = 0; rr < 16; ++rr) tmax = fmaxf(tmax, sa[kt][rr]);
      tmax = fmaxf(tmax, __shfl_xor(tmax, 32));

      if (!__all(tmax <= mrun + 11.5f)) {
        float mnew = fmaxf(mrun, tmax);
        float e = __builtin_amdgcn_exp2f(mrun - mnew);
        lrun *= e;
        mrun = mnew;
#pragma unroll
        for (int dt = 0; dt < 4; ++dt) o[dt] *= e;
      }

      float rsum = 0.f;
#pragma unroll
      for (int kt = 0; kt < 4; ++kt)
#pragma unroll
        for (int rr = 0; rr < 16; ++rr) {
          float p = __builtin_amdgcn_exp2f(sa[kt][rr] - mrun);
          sa[kt][rr] = p;
          rsum += p;
        }
      rsum += __shfl_xor(rsum, 32);
      lrun += rsum;

#pragma unroll
      for (int kt = 0; kt < 4; ++kt) {
#pragma unroll
        for (int u2 = 0; u2 < 2; ++u2) {
          int c = 4 * kt + 2 * u2 + h32;
          bf16x8 vf[4];
#pragma unroll
          for (int dt = 0; dt < 4; ++dt) {
            int row = dt * 32 + ql;
            vf[dt] = *(const bf16x8*)(Vc + row * 256 + ((c ^ swz0) << 4));
          }
          int A0, B0, A1, B1;
          asm("v_cvt_pk_bf16_f32 %0, %1, %2"
              : "=v"(A0) : "v"(sa[kt][u2 * 8 + 0]), "v"(sa[kt][u2 * 8 + 1]));
          asm("v_cvt_pk_bf16_f32 %0, %1, %2"
              : "=v"(B0) : "v"(sa[kt][u2 * 8 + 2]), "v"(sa[kt][u2 * 8 + 3]));
          asm("v_cvt_pk_bf16_f32 %0, %1, %2"
              : "=v"(A1) : "v"(sa[kt][u2 * 8 + 4]), "v"(sa[kt][u2 * 8 + 5]));
          asm("v_cvt_pk_bf16_f32 %0, %1, %2"
              : "=v"(B1) : "v"(sa[kt][u2 * 8 + 6]), "v"(sa[kt][u2 * 8 + 7]));
          auto r02 = __builtin_amdgcn_permlane32_swap(A0, A1, false, false);
          auto r13 = __builtin_amdgcn_permlane32_swap(B0, B1, false, false);
          union { int i[4]; bf16x8 v; } pu;
          pu.i[0] = r02[0];
          pu.i[1] = r13[0];
          pu.i[2] = r02[1];
          pu.i[3] = r13[1];
          __builtin_amdgcn_s_setprio(1);
#pragma unroll
          for (int dt = 0; dt < 4; ++dt)
            o[dt] = __builtin_amdgcn_mfma_f32_32x32x16_bf16(vf[dt], pu.v, o[dt],
                                                            0, 0, 0);
          __builtin_amdgcn_s_setprio(0);
        }
      }
    }
    asm volatile("s_waitcnt lgkmcnt(0)" ::: "memory");
    __builtin_amdgcn_s_barrier();
  }

  const int b = bh >> 4, h = bh & 15;
  float inv = 1.0f / lrun;
  size_t rowbase = ((size_t)b * 2048 + (wq0 + ql)) * 2048 + h * 128;
#pragma unroll
  for (int dt = 0; dt < 4; ++dt)
#pragma unroll
    for (int r4 = 0; r4 < 4; ++r4) {
      int col = dt * 32 + r4 * 8 + h32 * 4;
      ushort4 pk;
      pk.x = f2bf(o[dt][r4 * 4 + 0] * inv);
      pk.y = f2bf(o[dt][r4 * 4 + 1] * inv);
      pk.z = f2bf(o[dt][r4 * 4 + 2] * inv);
      pk.w = f2bf(o[dt][r4 * 4 + 3] * inv);
      *(ushort4*)(Og + rowbase + col) = pk;
    }
}

// ---------------------------------------------------------------- launch
extern "C" void kernel_launch(void* const* d_in, const int* in_sizes, int n_in,
                              void* d_out, int out_size, void* d_ws,
                              size_t ws_size, hipStream_t stream) {
  const float* x = (const float*)d_in[0];
  const float* w_qkv = (const float*)d_in[1];
  const float* b_qkv = (const float*)d_in[2];
  const float* w_out = (const float*)d_in[3];
  const float* b_out = (const float*)d_in[4];
  float* out = (float*)d_out;
  char* ws = (char*)d_ws;

  if (ws_size < 92274688u) return;
  ushort* xb = (ushort*)(ws);
  ushort* wqkvt = (ushort*)(ws + 16777216);
  ushort* Q = (ushort*)(ws + 41943040);
  ushort* Kb = (ushort*)(ws + 58720256);
  ushort* Vt = (ushort*)(ws + 75497472);
  ushort* comb = xb;
  ushort* woutt = wqkvt;

  // fused: x cast (8192 blocks) + w_qkv transpose (3072 blocks)
  prep_kernel<<<dim3(11264), 256, 0, stream>>>((const float4*)x, (ushort4*)xb,
                                               w_qkv, wqkvt);
  gemm_bt_kernel<1><<<dim3(48, 32), 256, 0, stream>>>(
      xb, wqkvt, b_qkv, nullptr, Q, Kb, Vt, 4096, 6144, 2048);
  transpose_cast_kernel<<<dim3(32, 32), 256, 0, stream>>>(w_out, woutt, 2048,
                                                          2048);
  attn_kernel<<<dim3(256), 512, 0, stream>>>(Q, Kb, Vt, comb);
  gemm_bt_kernel<0><<<dim3(16, 32), 256, 0, stream>>>(
      comb, woutt, b_out, out, nullptr, nullptr, nullptr, 4096, 2048, 2048);
}